// Round 3
// baseline (19421.729 us; speedup 1.0000x reference)
//
#include <hip/hip_runtime.h>
#include <cstddef>
#include <cstdint>

#define T_LEN 4096
#define FDIM  1024
#define H2DIM 1024
#define GDIM  4096   // 4*H2

#define NEGV (-10000.0f)
#define START_TAG 2
#define STOP_TAG 3

// ---- workspace layout (bytes) ----
#define XP_OFF      ((size_t)0)
#define XP_BYTES    ((size_t)2 * T_LEN * GDIM * 4)          // 134,217,728
#define HIST_OFF    (XP_OFF + XP_BYTES)
#define HIST_BYTES  ((size_t)T_LEN * 2048 * 4)              // 33,554,432
#define FEATS_OFF   (HIST_OFF + HIST_BYTES)
#define FEATS_BYTES ((size_t)T_LEN * 4 * 4)
#define SLOTS_OFF   (FEATS_OFF + FEATS_BYTES)
#define SLOTS_BYTES ((size_t)2 * 2 * 1024 * 8)              // parity x dir x unit, u64
#define WS_NEED     (SLOTS_OFF + SLOTS_BYTES)

__device__ __forceinline__ float sigm(float x) { return 1.0f / (1.0f + expf(-x)); }

// ============================================================================
// Kernel 1: xp[dir][s][j] = dot(x[row(s)], w_ih_dir[j]) + b_ih[j] + b_hh[j]
// dir=0: row=s ; dir=1: row = 4095-s (backward scan order).
// 128x128 tile, BK=32, 256 threads, 8x8 microtile. fp32 (no fp32 MFMA).
// ============================================================================
__global__ __launch_bounds__(256)
void xp_gemm(const float* __restrict__ x,
             const float* __restrict__ w_f, const float* __restrict__ w_b,
             const float* __restrict__ bi_f, const float* __restrict__ bh_f,
             const float* __restrict__ bi_b, const float* __restrict__ bh_b,
             float* __restrict__ xp)
{
    const int tid = threadIdx.x;
    const int dir = blockIdx.z;
    const int j0  = blockIdx.x * 128;
    const int t0  = blockIdx.y * 128;
    const float* __restrict__ w  = dir ? w_b  : w_f;
    const float* __restrict__ bi = dir ? bi_b : bi_f;
    const float* __restrict__ bh = dir ? bh_b : bh_f;

    __shared__ float As[32][133];   // [k][m], padded
    __shared__ float Bs[32][133];   // [k][n]

    const int tm0 = (tid & 15) * 8;
    const int tn0 = (tid >> 4) * 8;

    float acc[8][8];
    #pragma unroll
    for (int i = 0; i < 8; ++i)
        #pragma unroll
        for (int j = 0; j < 8; ++j) acc[i][j] = 0.f;

    const int lrow = tid >> 3;        // 0..31
    const int lkq  = (tid & 7) * 4;   // 0..28

    for (int kb = 0; kb < FDIM; kb += 32) {
        #pragma unroll
        for (int hh = 0; hh < 4; ++hh) {
            const int r  = lrow + hh * 32;            // 0..127
            const int tg = t0 + r;
            const int sr = dir ? (T_LEN - 1 - tg) : tg;
            const float4 av = *(const float4*)&x[(size_t)sr * FDIM + kb + lkq];
            As[lkq+0][r] = av.x; As[lkq+1][r] = av.y; As[lkq+2][r] = av.z; As[lkq+3][r] = av.w;
            const float4 bv = *(const float4*)&w[(size_t)(j0 + r) * FDIM + kb + lkq];
            Bs[lkq+0][r] = bv.x; Bs[lkq+1][r] = bv.y; Bs[lkq+2][r] = bv.z; Bs[lkq+3][r] = bv.w;
        }
        __syncthreads();
        #pragma unroll
        for (int k = 0; k < 32; ++k) {
            const float4 a0 = *(const float4*)&As[k][tm0];
            const float4 a1 = *(const float4*)&As[k][tm0 + 4];
            const float4 b0 = *(const float4*)&Bs[k][tn0];
            const float4 b1 = *(const float4*)&Bs[k][tn0 + 4];
            const float av[8] = {a0.x,a0.y,a0.z,a0.w,a1.x,a1.y,a1.z,a1.w};
            const float bv[8] = {b0.x,b0.y,b0.z,b0.w,b1.x,b1.y,b1.z,b1.w};
            #pragma unroll
            for (int i = 0; i < 8; ++i)
                #pragma unroll
                for (int j = 0; j < 8; ++j) acc[i][j] += av[i] * bv[j];
        }
        __syncthreads();
    }

    float bias[8];
    #pragma unroll
    for (int j = 0; j < 8; ++j) { const int col = j0 + tn0 + j; bias[j] = bi[col] + bh[col]; }

    float* __restrict__ xpd = xp + (size_t)dir * T_LEN * GDIM;
    #pragma unroll
    for (int i = 0; i < 8; ++i) {
        const int tr = t0 + tm0 + i;
        float4 o0, o1;
        o0.x = acc[i][0] + bias[0]; o0.y = acc[i][1] + bias[1];
        o0.z = acc[i][2] + bias[2]; o0.w = acc[i][3] + bias[3];
        o1.x = acc[i][4] + bias[4]; o1.y = acc[i][5] + bias[5];
        o1.z = acc[i][6] + bias[6]; o1.w = acc[i][7] + bias[7];
        *(float4*)&xpd[(size_t)tr * GDIM + j0 + tn0]     = o0;
        *(float4*)&xpd[(size_t)tr * GDIM + j0 + tn0 + 4] = o1;
    }
}

// ============================================================================
// Kernel 2: cooperative persistent bidirectional LSTM scan, v2.
// 256 blocks x 256 threads, 1 block/CU. w_hh held in REGISTERS (128 VGPR/thr).
// Thread (rg = tid>>5, kc = tid&31): owns ALL 4 gate rows of unit u0+rg,
// k-slice kc (8 strided float4). Value-merging butterfly (6 shfl) + 3 gather
// shfls put all 4 gate totals on lane kc==0 -> cell inline, no LDS round trip,
// ONE barrier per step. hbuf double-buffered by parity (pollers write next
// parity while laggards read current -> race-free single barrier).
// Publish h via 64-bit (tag|value) agent atomics; poll peers' slots directly.
// ============================================================================
__global__ __launch_bounds__(256, 1)
void lstm_scan(const float* __restrict__ xp,
               const float* __restrict__ h0,
               const float* __restrict__ c0,
               const float* __restrict__ whh_f,
               const float* __restrict__ whh_b,
               float* __restrict__ hist,
               unsigned long long* __restrict__ slots)
{
    __shared__ float hbuf[2][1024];   // 8 KB, parity double-buffer

    const int tid = threadIdx.x;
    const int b   = blockIdx.x;
    const int dir = b >> 7;
    const int bi  = b & 127;
    const int u0  = bi * 8;
    const int rg  = tid >> 5;   // unit index within block: 0..7
    const int kc  = tid & 31;   // k-slice: 8 float4 at s*128 + kc*4

    const float* __restrict__ whh = dir ? whh_b : whh_f;
    const size_t xpbase = (size_t)dir * T_LEN * GDIM;
    const int unit = u0 + rg;                 // global unit 0..1023

    // ---- stage w_hh rows (4 gates of `unit`) into registers: 128 VGPRs ----
    float4 wr[4][8];
    #pragma unroll
    for (int g = 0; g < 4; ++g) {
        const float* __restrict__ row = whh + ((size_t)(g << 10) + unit) * H2DIM;
        #pragma unroll
        for (int s = 0; s < 8; ++s)
            wr[g][s] = *(const float4*)&row[s * 128 + kc * 4];
    }

    // ---- init h, c, xp(t=0) ----
    *(float4*)&hbuf[0][tid * 4] = *(const float4*)&h0[dir * H2DIM + tid * 4];
    float creg = 0.f;
    float xpc[4] = {0.f, 0.f, 0.f, 0.f};
    if (kc == 0) {
        creg = c0[dir * H2DIM + unit];
        #pragma unroll
        for (int g = 0; g < 4; ++g) xpc[g] = xp[xpbase + (g << 10) + unit];
    }
    __syncthreads();

    int budget = 4000000;   // hang-proof poll budget

    for (int t = 0; t < T_LEN; ++t) {
        const float* __restrict__ hb = hbuf[t & 1];

        // prefetch next step's xp (hides HBM/L3 latency under compute)
        float xpn[4] = {0.f, 0.f, 0.f, 0.f};
        const int tnx = (t + 1 < T_LEN) ? (t + 1) : t;
        if (kc == 0) {
            #pragma unroll
            for (int g = 0; g < 4; ++g)
                xpn[g] = xp[xpbase + (size_t)tnx * GDIM + (g << 10) + unit];
        }

        // ---- partial dots: 4 gate rows x 32 k-elems, weights in registers ----
        float p0 = 0.f, p1 = 0.f, p2 = 0.f, p3 = 0.f;
        #pragma unroll
        for (int s = 0; s < 8; ++s) {
            const float4 hv = *(const float4*)&hb[s * 128 + kc * 4];
            p0 += wr[0][s].x*hv.x + wr[0][s].y*hv.y + wr[0][s].z*hv.z + wr[0][s].w*hv.w;
            p1 += wr[1][s].x*hv.x + wr[1][s].y*hv.y + wr[1][s].z*hv.z + wr[1][s].w*hv.w;
            p2 += wr[2][s].x*hv.x + wr[2][s].y*hv.y + wr[2][s].z*hv.z + wr[2][s].w*hv.w;
            p3 += wr[3][s].x*hv.x + wr[3][s].y*hv.y + wr[3][s].z*hv.z + wr[3][s].w*hv.w;
        }

        // ---- value-merging butterfly over 32 kc-lanes: 6 shfls ----
        // L1 (mask 1): merge (p0,p1) -> qa, (p2,p3) -> qb
        const bool o1 = (kc & 1);
        float sa = o1 ? p0 : p1;
        float ra = __shfl_xor(sa, 1);
        float qa = (o1 ? p1 : p0) + ra;
        float sb = o1 ? p2 : p3;
        float rb = __shfl_xor(sb, 1);
        float qb = (o1 ? p3 : p2) + rb;
        // L2 (mask 2): merge (qa,qb) -> r ; lane kc now owns gate (kc&3)
        const bool o2 = (kc & 2);
        float sc = o2 ? qa : qb;
        float rc = __shfl_xor(sc, 2);
        float r  = (o2 ? qb : qa) + rc;
        // L3..L5: plain butterfly
        r += __shfl_xor(r, 4);
        r += __shfl_xor(r, 8);
        r += __shfl_xor(r, 16);
        // gather gates 1..3 onto lane kc==0 (3 shfls)
        const float g1 = __shfl_xor(r, 1);
        const float g2 = __shfl_xor(r, 2);
        const float g3 = __shfl_xor(r, 3);

        // ---- cell + publish on lane kc==0 (one per unit) ----
        if (kc == 0) {
            const float gi = r  + xpc[0];
            const float gf = g1 + xpc[1];
            const float gg = g2 + xpc[2];
            const float go = g3 + xpc[3];
            const float c  = sigm(gf) * creg + sigm(gi) * tanhf(gg);
            const float h  = sigm(go) * tanhf(c);
            creg = c;
            const int tg = dir ? (T_LEN - 1 - t) : t;
            hist[(size_t)tg * 2048 + dir * H2DIM + unit] = h;
            const unsigned long long pack =
                ((unsigned long long)(unsigned)(t + 1) << 32) |
                (unsigned long long)__float_as_uint(h);
            __hip_atomic_store(&slots[((size_t)((t + 1) & 1) * 2 + dir) * H2DIM + unit],
                               pack, __ATOMIC_RELAXED, __HIP_MEMORY_SCOPE_AGENT);
        }

        // ---- poll peers' h for step t+1; write NEXT-parity hbuf ----
        if (t + 1 < T_LEN) {
            const unsigned want = (unsigned)(t + 1);
            unsigned long long* sb4 = &slots[((size_t)((t + 1) & 1) * 2 + dir) * H2DIM + tid * 4];
            unsigned long long v0 = 0, v1 = 0, v2 = 0, v3 = 0;
            bool d0 = false, d1 = false, d2 = false, d3 = false;
            for (;;) {
                if (!d0) v0 = __hip_atomic_load(&sb4[0], __ATOMIC_RELAXED, __HIP_MEMORY_SCOPE_AGENT);
                if (!d1) v1 = __hip_atomic_load(&sb4[1], __ATOMIC_RELAXED, __HIP_MEMORY_SCOPE_AGENT);
                if (!d2) v2 = __hip_atomic_load(&sb4[2], __ATOMIC_RELAXED, __HIP_MEMORY_SCOPE_AGENT);
                if (!d3) v3 = __hip_atomic_load(&sb4[3], __ATOMIC_RELAXED, __HIP_MEMORY_SCOPE_AGENT);
                d0 = d0 || ((unsigned)(v0 >> 32) == want);
                d1 = d1 || ((unsigned)(v1 >> 32) == want);
                d2 = d2 || ((unsigned)(v2 >> 32) == want);
                d3 = d3 || ((unsigned)(v3 >> 32) == want);
                if (d0 && d1 && d2 && d3) break;
                if (--budget <= 0) break;                // hang-proof bail
                __builtin_amdgcn_s_sleep(1);
            }
            float4 hv;
            hv.x = __uint_as_float((unsigned)v0);
            hv.y = __uint_as_float((unsigned)v1);
            hv.z = __uint_as_float((unsigned)v2);
            hv.w = __uint_as_float((unsigned)v3);
            *(float4*)&hbuf[(t + 1) & 1][tid * 4] = hv;
        }
        __syncthreads();   // next-parity hbuf complete; safe to proceed
        #pragma unroll
        for (int g = 0; g < 4; ++g) xpc[g] = xpn[g];
    }
}

// ============================================================================
// Kernel 3: feats[t][n] = dot(hist[t], w_tag[n]) + b_tag[n]
// ============================================================================
__global__ __launch_bounds__(256)
void feats_kernel(const float* __restrict__ hist,
                  const float* __restrict__ w_tag,
                  const float* __restrict__ b_tag,
                  float* __restrict__ feats)
{
    const int t = blockIdx.x;
    const int tid = threadIdx.x;
    const float* __restrict__ hrow = hist + (size_t)t * 2048 + tid * 8;
    const float4 ha = *(const float4*)&hrow[0];
    const float4 hb = *(const float4*)&hrow[4];
    float p[4];
    #pragma unroll
    for (int n = 0; n < 4; ++n) {
        const float* __restrict__ wr = w_tag + n * 2048 + tid * 8;
        const float4 wa = *(const float4*)&wr[0];
        const float4 wb = *(const float4*)&wr[4];
        p[n] = ha.x*wa.x + ha.y*wa.y + ha.z*wa.z + ha.w*wa.w
             + hb.x*wb.x + hb.y*wb.y + hb.z*wb.z + hb.w*wb.w;
    }
    #pragma unroll
    for (int m = 32; m >= 1; m >>= 1) {
        #pragma unroll
        for (int n = 0; n < 4; ++n) p[n] += __shfl_down(p[n], m);
    }
    __shared__ float red[4][4];
    const int wv = tid >> 6;
    if ((tid & 63) == 0) {
        #pragma unroll
        for (int n = 0; n < 4; ++n) red[n][wv] = p[n];
    }
    __syncthreads();
    if (tid < 4)
        feats[(size_t)t * 4 + tid] = red[tid][0] + red[tid][1] + red[tid][2] + red[tid][3] + b_tag[tid];
}

// ============================================================================
// Kernel 4: Viterbi (4 tags): forward DP + backtrace, op-order matches ref.
// ============================================================================
__global__ __launch_bounds__(256)
void viterbi_kernel(const float* __restrict__ feats,
                    const float* __restrict__ trans,
                    float* __restrict__ out)
{
    __shared__ float fsh[T_LEN * 4];   // 64 KB
    __shared__ unsigned bp[T_LEN];     // 16 KB
    const int tid = threadIdx.x;
    for (int i = tid; i < T_LEN; i += 256)
        *(float4*)&fsh[i * 4] = *(const float4*)&feats[(size_t)i * 4];
    __syncthreads();
    if (tid == 0) {
        float tr[16];
        #pragma unroll
        for (int i = 0; i < 16; ++i) tr[i] = trans[i];
        float fv[4] = {NEGV, NEGV, NEGV, NEGV};
        fv[START_TAG] = 0.0f;
        for (int t = 0; t < T_LEN; ++t) {
            float nf[4]; unsigned pb = 0;
            #pragma unroll
            for (int n = 0; n < 4; ++n) {
                float m = fv[0] + tr[n * 4 + 0]; int bsel = 0;
                #pragma unroll
                for (int p = 1; p < 4; ++p) {
                    const float s = fv[p] + tr[n * 4 + p];
                    if (s > m) { m = s; bsel = p; }
                }
                nf[n] = m + fsh[t * 4 + n];
                pb |= (unsigned)bsel << (8 * n);
            }
            bp[t] = pb;
            fv[0] = nf[0]; fv[1] = nf[1]; fv[2] = nf[2]; fv[3] = nf[3];
        }
        float bm = fv[0] + tr[STOP_TAG * 4 + 0]; int best = 0;
        #pragma unroll
        for (int p = 1; p < 4; ++p) {
            const float s = fv[p] + tr[STOP_TAG * 4 + p];
            if (s > bm) { bm = s; best = p; }
        }
        out[0] = bm;
        int cur = best;
        for (int t = T_LEN - 1; t >= 0; --t) {
            out[1 + t] = (float)cur;
            cur = (int)((bp[t] >> (8 * cur)) & 0xffu);
        }
    }
}

// ============================================================================
extern "C" void kernel_launch(void* const* d_in, const int* in_sizes, int n_in,
                              void* d_out, int out_size, void* d_ws, size_t ws_size,
                              hipStream_t stream) {
    const float* x      = (const float*)d_in[0];
    const float* h0     = (const float*)d_in[1];
    const float* c0     = (const float*)d_in[2];
    const float* w_ih_f = (const float*)d_in[3];
    const float* w_hh_f = (const float*)d_in[4];
    const float* b_ih_f = (const float*)d_in[5];
    const float* b_hh_f = (const float*)d_in[6];
    const float* w_ih_b = (const float*)d_in[7];
    const float* w_hh_b = (const float*)d_in[8];
    const float* b_ih_b = (const float*)d_in[9];
    const float* b_hh_b = (const float*)d_in[10];
    const float* w_tag  = (const float*)d_in[11];
    const float* b_tag  = (const float*)d_in[12];
    const float* trans  = (const float*)d_in[13];
    float* out = (float*)d_out;

    if (ws_size < WS_NEED) return;   // signature: output stays poisoned

    char* ws = (char*)d_ws;
    float* xp    = (float*)(ws + XP_OFF);
    float* hist  = (float*)(ws + HIST_OFF);
    float* feats = (float*)(ws + FEATS_OFF);
    unsigned long long* slots = (unsigned long long*)(ws + SLOTS_OFF);

    hipMemsetAsync(slots, 0, SLOTS_BYTES, stream);

    dim3 ggrid(32, 32, 2);
    xp_gemm<<<ggrid, 256, 0, stream>>>(x, w_ih_f, w_ih_b, b_ih_f, b_hh_f, b_ih_b, b_hh_b, xp);

    void* ka[] = { (void*)&xp, (void*)&h0, (void*)&c0, (void*)&w_hh_f, (void*)&w_hh_b,
                   (void*)&hist, (void*)&slots };
    hipLaunchCooperativeKernel((void*)lstm_scan, dim3(256), dim3(256), ka, 0, stream);

    feats_kernel<<<T_LEN, 256, 0, stream>>>(hist, w_tag, b_tag, feats);
    viterbi_kernel<<<1, 256, 0, stream>>>(feats, trans, out);
}

// Round 4
// 19189.958 us; speedup vs baseline: 1.0121x; 1.0121x over previous
//
#include <hip/hip_runtime.h>
#include <cstddef>
#include <cstdint>

#define T_LEN 4096
#define FDIM  1024
#define H2DIM 1024
#define GDIM  4096   // 4*H2

#define NEGV (-10000.0f)
#define START_TAG 2
#define STOP_TAG 3

// ---- workspace layout (bytes) ----
#define XP_OFF      ((size_t)0)
#define XP_BYTES    ((size_t)2 * T_LEN * GDIM * 4)          // 134,217,728
#define HIST_OFF    (XP_OFF + XP_BYTES)
#define HIST_BYTES  ((size_t)T_LEN * 2048 * 4)              // 33,554,432
#define FEATS_OFF   (HIST_OFF + HIST_BYTES)
#define FEATS_BYTES ((size_t)T_LEN * 4 * 4)
#define SLOTS_OFF   (FEATS_OFF + FEATS_BYTES)
#define SLOTS_BYTES ((size_t)2 * 2 * 1024 * 8)              // parity x dir x unit, u64
#define WS_NEED     (SLOTS_OFF + SLOTS_BYTES)

__device__ __forceinline__ float sigm(float x) { return 1.0f / (1.0f + expf(-x)); }

// ============================================================================
// Kernel 1: xp[dir][s][j] = dot(x[row(s)], w_ih_dir[j]) + b_ih[j] + b_hh[j]
// dir=0: row=s ; dir=1: row = 4095-s (backward scan order).
// 128x128 tile, BK=32, 256 threads, 8x8 microtile. fp32 (no fp32 MFMA).
// ============================================================================
__global__ __launch_bounds__(256)
void xp_gemm(const float* __restrict__ x,
             const float* __restrict__ w_f, const float* __restrict__ w_b,
             const float* __restrict__ bi_f, const float* __restrict__ bh_f,
             const float* __restrict__ bi_b, const float* __restrict__ bh_b,
             float* __restrict__ xp)
{
    const int tid = threadIdx.x;
    const int dir = blockIdx.z;
    const int j0  = blockIdx.x * 128;
    const int t0  = blockIdx.y * 128;
    const float* __restrict__ w  = dir ? w_b  : w_f;
    const float* __restrict__ bi = dir ? bi_b : bi_f;
    const float* __restrict__ bh = dir ? bh_b : bh_f;

    __shared__ float As[32][133];   // [k][m], padded
    __shared__ float Bs[32][133];   // [k][n]

    const int tm0 = (tid & 15) * 8;
    const int tn0 = (tid >> 4) * 8;

    float acc[8][8];
    #pragma unroll
    for (int i = 0; i < 8; ++i)
        #pragma unroll
        for (int j = 0; j < 8; ++j) acc[i][j] = 0.f;

    const int lrow = tid >> 3;        // 0..31
    const int lkq  = (tid & 7) * 4;   // 0..28

    for (int kb = 0; kb < FDIM; kb += 32) {
        #pragma unroll
        for (int hh = 0; hh < 4; ++hh) {
            const int r  = lrow + hh * 32;            // 0..127
            const int tg = t0 + r;
            const int sr = dir ? (T_LEN - 1 - tg) : tg;
            const float4 av = *(const float4*)&x[(size_t)sr * FDIM + kb + lkq];
            As[lkq+0][r] = av.x; As[lkq+1][r] = av.y; As[lkq+2][r] = av.z; As[lkq+3][r] = av.w;
            const float4 bv = *(const float4*)&w[(size_t)(j0 + r) * FDIM + kb + lkq];
            Bs[lkq+0][r] = bv.x; Bs[lkq+1][r] = bv.y; Bs[lkq+2][r] = bv.z; Bs[lkq+3][r] = bv.w;
        }
        __syncthreads();
        #pragma unroll
        for (int k = 0; k < 32; ++k) {
            const float4 a0 = *(const float4*)&As[k][tm0];
            const float4 a1 = *(const float4*)&As[k][tm0 + 4];
            const float4 b0 = *(const float4*)&Bs[k][tn0];
            const float4 b1 = *(const float4*)&Bs[k][tn0 + 4];
            const float av[8] = {a0.x,a0.y,a0.z,a0.w,a1.x,a1.y,a1.z,a1.w};
            const float bv[8] = {b0.x,b0.y,b0.z,b0.w,b1.x,b1.y,b1.z,b1.w};
            #pragma unroll
            for (int i = 0; i < 8; ++i)
                #pragma unroll
                for (int j = 0; j < 8; ++j) acc[i][j] += av[i] * bv[j];
        }
        __syncthreads();
    }

    float bias[8];
    #pragma unroll
    for (int j = 0; j < 8; ++j) { const int col = j0 + tn0 + j; bias[j] = bi[col] + bh[col]; }

    float* __restrict__ xpd = xp + (size_t)dir * T_LEN * GDIM;
    #pragma unroll
    for (int i = 0; i < 8; ++i) {
        const int tr = t0 + tm0 + i;
        float4 o0, o1;
        o0.x = acc[i][0] + bias[0]; o0.y = acc[i][1] + bias[1];
        o0.z = acc[i][2] + bias[2]; o0.w = acc[i][3] + bias[3];
        o1.x = acc[i][4] + bias[4]; o1.y = acc[i][5] + bias[5];
        o1.z = acc[i][6] + bias[6]; o1.w = acc[i][7] + bias[7];
        *(float4*)&xpd[(size_t)tr * GDIM + j0 + tn0]     = o0;
        *(float4*)&xpd[(size_t)tr * GDIM + j0 + tn0 + 4] = o1;
    }
}

// ============================================================================
// Kernel 2: cooperative persistent bidirectional LSTM scan, v3.
// Same schedule as v2 (single barrier, value-merging butterfly, parity-
// double-buffered hbuf, packed-slot sync) but w_hh is held in 32 NAMED
// float4 registers per thread (the v2 float4[4][8] array was demoted to
// scratch by hipcc -> +1.0us/step L2 reload; named scalars cannot be demoted).
// ============================================================================
#define DOT4(a,b) ((a).x*(b).x + (a).y*(b).y + (a).z*(b).z + (a).w*(b).w)

__global__ __launch_bounds__(256, 1)
void lstm_scan(const float* __restrict__ xp,
               const float* __restrict__ h0,
               const float* __restrict__ c0,
               const float* __restrict__ whh_f,
               const float* __restrict__ whh_b,
               float* __restrict__ hist,
               unsigned long long* __restrict__ slots)
{
    __shared__ float hbuf[2][1024];   // 8 KB, parity double-buffer

    const int tid = threadIdx.x;
    const int b   = blockIdx.x;
    const int dir = b >> 7;
    const int bi  = b & 127;
    const int u0  = bi * 8;
    const int rg  = tid >> 5;   // unit index within block: 0..7
    const int kc  = tid & 31;   // k-slice: 8 float4 at s*128 + kc*4

    const float* __restrict__ whh = dir ? whh_b : whh_f;
    const size_t xpbase = (size_t)dir * T_LEN * GDIM;
    const int unit = u0 + rg;                 // global unit 0..1023

    // ---- stage w_hh rows (4 gates of `unit`) into 32 NAMED float4 regs ----
    float4 w00,w01,w02,w03,w04,w05,w06,w07;
    float4 w10,w11,w12,w13,w14,w15,w16,w17;
    float4 w20,w21,w22,w23,w24,w25,w26,w27;
    float4 w30,w31,w32,w33,w34,w35,w36,w37;
    {
        const float* __restrict__ r0 = whh + ((size_t)(0 << 10) + unit) * H2DIM + kc * 4;
        w00=*(const float4*)&r0[  0]; w01=*(const float4*)&r0[128]; w02=*(const float4*)&r0[256]; w03=*(const float4*)&r0[384];
        w04=*(const float4*)&r0[512]; w05=*(const float4*)&r0[640]; w06=*(const float4*)&r0[768]; w07=*(const float4*)&r0[896];
        const float* __restrict__ r1 = whh + ((size_t)(1 << 10) + unit) * H2DIM + kc * 4;
        w10=*(const float4*)&r1[  0]; w11=*(const float4*)&r1[128]; w12=*(const float4*)&r1[256]; w13=*(const float4*)&r1[384];
        w14=*(const float4*)&r1[512]; w15=*(const float4*)&r1[640]; w16=*(const float4*)&r1[768]; w17=*(const float4*)&r1[896];
        const float* __restrict__ r2 = whh + ((size_t)(2 << 10) + unit) * H2DIM + kc * 4;
        w20=*(const float4*)&r2[  0]; w21=*(const float4*)&r2[128]; w22=*(const float4*)&r2[256]; w23=*(const float4*)&r2[384];
        w24=*(const float4*)&r2[512]; w25=*(const float4*)&r2[640]; w26=*(const float4*)&r2[768]; w27=*(const float4*)&r2[896];
        const float* __restrict__ r3 = whh + ((size_t)(3 << 10) + unit) * H2DIM + kc * 4;
        w30=*(const float4*)&r3[  0]; w31=*(const float4*)&r3[128]; w32=*(const float4*)&r3[256]; w33=*(const float4*)&r3[384];
        w34=*(const float4*)&r3[512]; w35=*(const float4*)&r3[640]; w36=*(const float4*)&r3[768]; w37=*(const float4*)&r3[896];
    }

    // ---- init h, c, xp(t=0) ----
    *(float4*)&hbuf[0][tid * 4] = *(const float4*)&h0[dir * H2DIM + tid * 4];
    float creg = 0.f;
    float xpc0 = 0.f, xpc1 = 0.f, xpc2 = 0.f, xpc3 = 0.f;
    if (kc == 0) {
        creg = c0[dir * H2DIM + unit];
        xpc0 = xp[xpbase + (0 << 10) + unit];
        xpc1 = xp[xpbase + (1 << 10) + unit];
        xpc2 = xp[xpbase + (2 << 10) + unit];
        xpc3 = xp[xpbase + (3 << 10) + unit];
    }
    __syncthreads();

    int budget = 4000000;   // hang-proof poll budget

    for (int t = 0; t < T_LEN; ++t) {
        const float* __restrict__ hb = hbuf[t & 1];

        // prefetch next step's xp (hides HBM/L3 latency under compute)
        float xpn0 = 0.f, xpn1 = 0.f, xpn2 = 0.f, xpn3 = 0.f;
        const int tnx = (t + 1 < T_LEN) ? (t + 1) : t;
        if (kc == 0) {
            const size_t base = xpbase + (size_t)tnx * GDIM + unit;
            xpn0 = xp[base];
            xpn1 = xp[base + 1024];
            xpn2 = xp[base + 2048];
            xpn3 = xp[base + 3072];
        }

        // ---- h slices from LDS (broadcast across the two 32-lane halves) ----
        const float4 hv0 = *(const float4*)&hb[      kc * 4];
        const float4 hv1 = *(const float4*)&hb[128 + kc * 4];
        const float4 hv2 = *(const float4*)&hb[256 + kc * 4];
        const float4 hv3 = *(const float4*)&hb[384 + kc * 4];
        const float4 hv4 = *(const float4*)&hb[512 + kc * 4];
        const float4 hv5 = *(const float4*)&hb[640 + kc * 4];
        const float4 hv6 = *(const float4*)&hb[768 + kc * 4];
        const float4 hv7 = *(const float4*)&hb[896 + kc * 4];

        // ---- partial dots: 4 gate rows x 32 k-elems, weights in registers ----
        float p0 = DOT4(w00,hv0)+DOT4(w01,hv1)+DOT4(w02,hv2)+DOT4(w03,hv3)
                 + DOT4(w04,hv4)+DOT4(w05,hv5)+DOT4(w06,hv6)+DOT4(w07,hv7);
        float p1 = DOT4(w10,hv0)+DOT4(w11,hv1)+DOT4(w12,hv2)+DOT4(w13,hv3)
                 + DOT4(w14,hv4)+DOT4(w15,hv5)+DOT4(w16,hv6)+DOT4(w17,hv7);
        float p2 = DOT4(w20,hv0)+DOT4(w21,hv1)+DOT4(w22,hv2)+DOT4(w23,hv3)
                 + DOT4(w24,hv4)+DOT4(w25,hv5)+DOT4(w26,hv6)+DOT4(w27,hv7);
        float p3 = DOT4(w30,hv0)+DOT4(w31,hv1)+DOT4(w32,hv2)+DOT4(w33,hv3)
                 + DOT4(w34,hv4)+DOT4(w35,hv5)+DOT4(w36,hv6)+DOT4(w37,hv7);

        // ---- value-merging butterfly over 32 kc-lanes: 6 shfls ----
        const bool o1 = (kc & 1);
        float sa = o1 ? p0 : p1;
        float ra = __shfl_xor(sa, 1);
        float qa = (o1 ? p1 : p0) + ra;
        float sb = o1 ? p2 : p3;
        float rb = __shfl_xor(sb, 1);
        float qb = (o1 ? p3 : p2) + rb;
        const bool o2 = (kc & 2);
        float sc = o2 ? qa : qb;
        float rc = __shfl_xor(sc, 2);
        float r  = (o2 ? qb : qa) + rc;
        r += __shfl_xor(r, 4);
        r += __shfl_xor(r, 8);
        r += __shfl_xor(r, 16);
        // gather gates 1..3 onto lane kc==0 (3 shfls)
        const float g1 = __shfl_xor(r, 1);
        const float g2 = __shfl_xor(r, 2);
        const float g3 = __shfl_xor(r, 3);

        // ---- cell + publish on lane kc==0 (one per unit) ----
        if (kc == 0) {
            const float gi = r  + xpc0;
            const float gf = g1 + xpc1;
            const float gg = g2 + xpc2;
            const float go = g3 + xpc3;
            const float c  = sigm(gf) * creg + sigm(gi) * tanhf(gg);
            const float h  = sigm(go) * tanhf(c);
            creg = c;
            const int tg = dir ? (T_LEN - 1 - t) : t;
            hist[(size_t)tg * 2048 + dir * H2DIM + unit] = h;
            const unsigned long long pack =
                ((unsigned long long)(unsigned)(t + 1) << 32) |
                (unsigned long long)__float_as_uint(h);
            __hip_atomic_store(&slots[((size_t)((t + 1) & 1) * 2 + dir) * H2DIM + unit],
                               pack, __ATOMIC_RELAXED, __HIP_MEMORY_SCOPE_AGENT);
        }

        // ---- poll peers' h for step t+1; write NEXT-parity hbuf ----
        if (t + 1 < T_LEN) {
            const unsigned want = (unsigned)(t + 1);
            unsigned long long* sb4 = &slots[((size_t)((t + 1) & 1) * 2 + dir) * H2DIM + tid * 4];
            unsigned long long v0 = 0, v1 = 0, v2 = 0, v3 = 0;
            bool d0 = false, d1 = false, d2 = false, d3 = false;
            for (;;) {
                if (!d0) v0 = __hip_atomic_load(&sb4[0], __ATOMIC_RELAXED, __HIP_MEMORY_SCOPE_AGENT);
                if (!d1) v1 = __hip_atomic_load(&sb4[1], __ATOMIC_RELAXED, __HIP_MEMORY_SCOPE_AGENT);
                if (!d2) v2 = __hip_atomic_load(&sb4[2], __ATOMIC_RELAXED, __HIP_MEMORY_SCOPE_AGENT);
                if (!d3) v3 = __hip_atomic_load(&sb4[3], __ATOMIC_RELAXED, __HIP_MEMORY_SCOPE_AGENT);
                d0 = d0 || ((unsigned)(v0 >> 32) == want);
                d1 = d1 || ((unsigned)(v1 >> 32) == want);
                d2 = d2 || ((unsigned)(v2 >> 32) == want);
                d3 = d3 || ((unsigned)(v3 >> 32) == want);
                if (d0 && d1 && d2 && d3) break;
                if (--budget <= 0) break;                // hang-proof bail
                __builtin_amdgcn_s_sleep(1);
            }
            float4 hv;
            hv.x = __uint_as_float((unsigned)v0);
            hv.y = __uint_as_float((unsigned)v1);
            hv.z = __uint_as_float((unsigned)v2);
            hv.w = __uint_as_float((unsigned)v3);
            *(float4*)&hbuf[(t + 1) & 1][tid * 4] = hv;
        }
        __syncthreads();   // next-parity hbuf complete; safe to proceed
        xpc0 = xpn0; xpc1 = xpn1; xpc2 = xpn2; xpc3 = xpn3;
    }
}

// ============================================================================
// Kernel 3: feats[t][n] = dot(hist[t], w_tag[n]) + b_tag[n]
// ============================================================================
__global__ __launch_bounds__(256)
void feats_kernel(const float* __restrict__ hist,
                  const float* __restrict__ w_tag,
                  const float* __restrict__ b_tag,
                  float* __restrict__ feats)
{
    const int t = blockIdx.x;
    const int tid = threadIdx.x;
    const float* __restrict__ hrow = hist + (size_t)t * 2048 + tid * 8;
    const float4 ha = *(const float4*)&hrow[0];
    const float4 hb = *(const float4*)&hrow[4];
    float p[4];
    #pragma unroll
    for (int n = 0; n < 4; ++n) {
        const float* __restrict__ wr = w_tag + n * 2048 + tid * 8;
        const float4 wa = *(const float4*)&wr[0];
        const float4 wb = *(const float4*)&wr[4];
        p[n] = ha.x*wa.x + ha.y*wa.y + ha.z*wa.z + ha.w*wa.w
             + hb.x*wb.x + hb.y*wb.y + hb.z*wb.z + hb.w*wb.w;
    }
    #pragma unroll
    for (int m = 32; m >= 1; m >>= 1) {
        #pragma unroll
        for (int n = 0; n < 4; ++n) p[n] += __shfl_down(p[n], m);
    }
    __shared__ float red[4][4];
    const int wv = tid >> 6;
    if ((tid & 63) == 0) {
        #pragma unroll
        for (int n = 0; n < 4; ++n) red[n][wv] = p[n];
    }
    __syncthreads();
    if (tid < 4)
        feats[(size_t)t * 4 + tid] = red[tid][0] + red[tid][1] + red[tid][2] + red[tid][3] + b_tag[tid];
}

// ============================================================================
// Kernel 4: Viterbi (4 tags): forward DP + backtrace, op-order matches ref.
// ============================================================================
__global__ __launch_bounds__(256)
void viterbi_kernel(const float* __restrict__ feats,
                    const float* __restrict__ trans,
                    float* __restrict__ out)
{
    __shared__ float fsh[T_LEN * 4];   // 64 KB
    __shared__ unsigned bp[T_LEN];     // 16 KB
    const int tid = threadIdx.x;
    for (int i = tid; i < T_LEN; i += 256)
        *(float4*)&fsh[i * 4] = *(const float4*)&feats[(size_t)i * 4];
    __syncthreads();
    if (tid == 0) {
        float tr[16];
        #pragma unroll
        for (int i = 0; i < 16; ++i) tr[i] = trans[i];
        float fv[4] = {NEGV, NEGV, NEGV, NEGV};
        fv[START_TAG] = 0.0f;
        for (int t = 0; t < T_LEN; ++t) {
            float nf[4]; unsigned pb = 0;
            #pragma unroll
            for (int n = 0; n < 4; ++n) {
                float m = fv[0] + tr[n * 4 + 0]; int bsel = 0;
                #pragma unroll
                for (int p = 1; p < 4; ++p) {
                    const float s = fv[p] + tr[n * 4 + p];
                    if (s > m) { m = s; bsel = p; }
                }
                nf[n] = m + fsh[t * 4 + n];
                pb |= (unsigned)bsel << (8 * n);
            }
            bp[t] = pb;
            fv[0] = nf[0]; fv[1] = nf[1]; fv[2] = nf[2]; fv[3] = nf[3];
        }
        float bm = fv[0] + tr[STOP_TAG * 4 + 0]; int best = 0;
        #pragma unroll
        for (int p = 1; p < 4; ++p) {
            const float s = fv[p] + tr[STOP_TAG * 4 + p];
            if (s > bm) { bm = s; best = p; }
        }
        out[0] = bm;
        int cur = best;
        for (int t = T_LEN - 1; t >= 0; --t) {
            out[1 + t] = (float)cur;
            cur = (int)((bp[t] >> (8 * cur)) & 0xffu);
        }
    }
}

// ============================================================================
extern "C" void kernel_launch(void* const* d_in, const int* in_sizes, int n_in,
                              void* d_out, int out_size, void* d_ws, size_t ws_size,
                              hipStream_t stream) {
    const float* x      = (const float*)d_in[0];
    const float* h0     = (const float*)d_in[1];
    const float* c0     = (const float*)d_in[2];
    const float* w_ih_f = (const float*)d_in[3];
    const float* w_hh_f = (const float*)d_in[4];
    const float* b_ih_f = (const float*)d_in[5];
    const float* b_hh_f = (const float*)d_in[6];
    const float* w_ih_b = (const float*)d_in[7];
    const float* w_hh_b = (const float*)d_in[8];
    const float* b_ih_b = (const float*)d_in[9];
    const float* b_hh_b = (const float*)d_in[10];
    const float* w_tag  = (const float*)d_in[11];
    const float* b_tag  = (const float*)d_in[12];
    const float* trans  = (const float*)d_in[13];
    float* out = (float*)d_out;

    if (ws_size < WS_NEED) return;   // signature: output stays poisoned

    char* ws = (char*)d_ws;
    float* xp    = (float*)(ws + XP_OFF);
    float* hist  = (float*)(ws + HIST_OFF);
    float* feats = (float*)(ws + FEATS_OFF);
    unsigned long long* slots = (unsigned long long*)(ws + SLOTS_OFF);

    hipMemsetAsync(slots, 0, SLOTS_BYTES, stream);

    dim3 ggrid(32, 32, 2);
    xp_gemm<<<ggrid, 256, 0, stream>>>(x, w_ih_f, w_ih_b, b_ih_f, b_hh_f, b_ih_b, b_hh_b, xp);

    void* ka[] = { (void*)&xp, (void*)&h0, (void*)&c0, (void*)&w_hh_f, (void*)&w_hh_b,
                   (void*)&hist, (void*)&slots };
    hipLaunchCooperativeKernel((void*)lstm_scan, dim3(256), dim3(256), ka, 0, stream);

    feats_kernel<<<T_LEN, 256, 0, stream>>>(hist, w_tag, b_tag, feats);
    viterbi_kernel<<<1, 256, 0, stream>>>(feats, trans, out);
}

// Round 5
// 17726.247 us; speedup vs baseline: 1.0956x; 1.0826x over previous
//
#include <hip/hip_runtime.h>
#include <cstddef>
#include <cstdint>

#define T_LEN 4096
#define FDIM  1024
#define H2DIM 1024
#define GDIM  4096   // 4*H2

#define NEGV (-10000.0f)
#define START_TAG 2
#define STOP_TAG 3

// ---- workspace layout (bytes) ----
#define XP_OFF      ((size_t)0)
#define XP_BYTES    ((size_t)2 * T_LEN * GDIM * 4)          // 134,217,728
#define HIST_OFF    (XP_OFF + XP_BYTES)
#define HIST_BYTES  ((size_t)T_LEN * 2048 * 4)              // 33,554,432
#define FEATS_OFF   (HIST_OFF + HIST_BYTES)
#define FEATS_BYTES ((size_t)T_LEN * 4 * 4)
#define SLOTS_OFF   (FEATS_OFF + FEATS_BYTES)
#define SLOTS_BYTES ((size_t)2 * 2 * 1024 * 8)              // parity x dir x unit, u64
#define WS_NEED     (SLOTS_OFF + SLOTS_BYTES)

__device__ __forceinline__ float sigm(float x) { return 1.0f / (1.0f + expf(-x)); }

// ============================================================================
// Kernel 1: xp[dir][s][j] = dot(x[row(s)], w_ih_dir[j]) + b_ih[j] + b_hh[j]
// dir=0: row=s ; dir=1: row = 4095-s (backward scan order).
// 128x128 tile, BK=32, 256 threads, 8x8 microtile. fp32 (no fp32 MFMA).
// ============================================================================
__global__ __launch_bounds__(256)
void xp_gemm(const float* __restrict__ x,
             const float* __restrict__ w_f, const float* __restrict__ w_b,
             const float* __restrict__ bi_f, const float* __restrict__ bh_f,
             const float* __restrict__ bi_b, const float* __restrict__ bh_b,
             float* __restrict__ xp)
{
    const int tid = threadIdx.x;
    const int dir = blockIdx.z;
    const int j0  = blockIdx.x * 128;
    const int t0  = blockIdx.y * 128;
    const float* __restrict__ w  = dir ? w_b  : w_f;
    const float* __restrict__ bi = dir ? bi_b : bi_f;
    const float* __restrict__ bh = dir ? bh_b : bh_f;

    __shared__ float As[32][133];   // [k][m], padded
    __shared__ float Bs[32][133];   // [k][n]

    const int tm0 = (tid & 15) * 8;
    const int tn0 = (tid >> 4) * 8;

    float acc[8][8];
    #pragma unroll
    for (int i = 0; i < 8; ++i)
        #pragma unroll
        for (int j = 0; j < 8; ++j) acc[i][j] = 0.f;

    const int lrow = tid >> 3;        // 0..31
    const int lkq  = (tid & 7) * 4;   // 0..28

    for (int kb = 0; kb < FDIM; kb += 32) {
        #pragma unroll
        for (int hh = 0; hh < 4; ++hh) {
            const int r  = lrow + hh * 32;            // 0..127
            const int tg = t0 + r;
            const int sr = dir ? (T_LEN - 1 - tg) : tg;
            const float4 av = *(const float4*)&x[(size_t)sr * FDIM + kb + lkq];
            As[lkq+0][r] = av.x; As[lkq+1][r] = av.y; As[lkq+2][r] = av.z; As[lkq+3][r] = av.w;
            const float4 bv = *(const float4*)&w[(size_t)(j0 + r) * FDIM + kb + lkq];
            Bs[lkq+0][r] = bv.x; Bs[lkq+1][r] = bv.y; Bs[lkq+2][r] = bv.z; Bs[lkq+3][r] = bv.w;
        }
        __syncthreads();
        #pragma unroll
        for (int k = 0; k < 32; ++k) {
            const float4 a0 = *(const float4*)&As[k][tm0];
            const float4 a1 = *(const float4*)&As[k][tm0 + 4];
            const float4 b0 = *(const float4*)&Bs[k][tn0];
            const float4 b1 = *(const float4*)&Bs[k][tn0 + 4];
            const float av[8] = {a0.x,a0.y,a0.z,a0.w,a1.x,a1.y,a1.z,a1.w};
            const float bv[8] = {b0.x,b0.y,b0.z,b0.w,b1.x,b1.y,b1.z,b1.w};
            #pragma unroll
            for (int i = 0; i < 8; ++i)
                #pragma unroll
                for (int j = 0; j < 8; ++j) acc[i][j] += av[i] * bv[j];
        }
        __syncthreads();
    }

    float bias[8];
    #pragma unroll
    for (int j = 0; j < 8; ++j) { const int col = j0 + tn0 + j; bias[j] = bi[col] + bh[col]; }

    float* __restrict__ xpd = xp + (size_t)dir * T_LEN * GDIM;
    #pragma unroll
    for (int i = 0; i < 8; ++i) {
        const int tr = t0 + tm0 + i;
        float4 o0, o1;
        o0.x = acc[i][0] + bias[0]; o0.y = acc[i][1] + bias[1];
        o0.z = acc[i][2] + bias[2]; o0.w = acc[i][3] + bias[3];
        o1.x = acc[i][4] + bias[4]; o1.y = acc[i][5] + bias[5];
        o1.z = acc[i][6] + bias[6]; o1.w = acc[i][7] + bias[7];
        *(float4*)&xpd[(size_t)tr * GDIM + j0 + tn0]     = o0;
        *(float4*)&xpd[(size_t)tr * GDIM + j0 + tn0 + 4] = o1;
    }
}

// ============================================================================
// Kernel 2: cooperative persistent bidirectional LSTM scan, v4.
// v2 schedule (single barrier, value-merging butterfly, parity hbuf, packed-
// slot sync) + weights PINNED in VGPRs via asm opacity: R3's array went to
// scratch, R4's named floats got load-REMATERIALIZED (VGPR=96, 512B/thr/step
// global re-read). asm volatile("":"+v") makes the loaded values opaque ->
// regalloc must keep ~190 VGPRs live (budget 512 at launch_bounds(256,1)).
// Depth-2 xp prefetch so poll-loop vmcnt(0) never waits on a fresh HBM miss.
// ============================================================================
#define DOT4(a,b) ((a).x*(b).x + (a).y*(b).y + (a).z*(b).z + (a).w*(b).w)
#define PIN4(v) asm volatile("" : "+v"((v).x), "+v"((v).y), "+v"((v).z), "+v"((v).w))

__global__ __launch_bounds__(256, 1)
void lstm_scan(const float* __restrict__ xp,
               const float* __restrict__ h0,
               const float* __restrict__ c0,
               const float* __restrict__ whh_f,
               const float* __restrict__ whh_b,
               float* __restrict__ hist,
               unsigned long long* __restrict__ slots)
{
    __shared__ float hbuf[2][1024];   // 8 KB, parity double-buffer

    const int tid = threadIdx.x;
    const int b   = blockIdx.x;
    const int dir = b >> 7;
    const int bi  = b & 127;
    const int u0  = bi * 8;
    const int rg  = tid >> 5;   // unit index within block: 0..7
    const int kc  = tid & 31;   // k-slice: 8 float4 at s*128 + kc*4

    const float* __restrict__ whh = dir ? whh_b : whh_f;
    const size_t xpbase = (size_t)dir * T_LEN * GDIM;
    const int unit = u0 + rg;                 // global unit 0..1023

    // ---- stage w_hh rows (4 gates of `unit`) into 32 pinned float4 regs ----
    float4 w00,w01,w02,w03,w04,w05,w06,w07;
    float4 w10,w11,w12,w13,w14,w15,w16,w17;
    float4 w20,w21,w22,w23,w24,w25,w26,w27;
    float4 w30,w31,w32,w33,w34,w35,w36,w37;
    {
        const float* __restrict__ r0 = whh + ((size_t)(0 << 10) + unit) * H2DIM + kc * 4;
        w00=*(const float4*)&r0[  0]; w01=*(const float4*)&r0[128]; w02=*(const float4*)&r0[256]; w03=*(const float4*)&r0[384];
        w04=*(const float4*)&r0[512]; w05=*(const float4*)&r0[640]; w06=*(const float4*)&r0[768]; w07=*(const float4*)&r0[896];
        const float* __restrict__ r1 = whh + ((size_t)(1 << 10) + unit) * H2DIM + kc * 4;
        w10=*(const float4*)&r1[  0]; w11=*(const float4*)&r1[128]; w12=*(const float4*)&r1[256]; w13=*(const float4*)&r1[384];
        w14=*(const float4*)&r1[512]; w15=*(const float4*)&r1[640]; w16=*(const float4*)&r1[768]; w17=*(const float4*)&r1[896];
        const float* __restrict__ r2 = whh + ((size_t)(2 << 10) + unit) * H2DIM + kc * 4;
        w20=*(const float4*)&r2[  0]; w21=*(const float4*)&r2[128]; w22=*(const float4*)&r2[256]; w23=*(const float4*)&r2[384];
        w24=*(const float4*)&r2[512]; w25=*(const float4*)&r2[640]; w26=*(const float4*)&r2[768]; w27=*(const float4*)&r2[896];
        const float* __restrict__ r3 = whh + ((size_t)(3 << 10) + unit) * H2DIM + kc * 4;
        w30=*(const float4*)&r3[  0]; w31=*(const float4*)&r3[128]; w32=*(const float4*)&r3[256]; w33=*(const float4*)&r3[384];
        w34=*(const float4*)&r3[512]; w35=*(const float4*)&r3[640]; w36=*(const float4*)&r3[768]; w37=*(const float4*)&r3[896];
    }
    // pin: values become asm-opaque -> cannot be rematerialized from memory
    PIN4(w00); PIN4(w01); PIN4(w02); PIN4(w03); PIN4(w04); PIN4(w05); PIN4(w06); PIN4(w07);
    PIN4(w10); PIN4(w11); PIN4(w12); PIN4(w13); PIN4(w14); PIN4(w15); PIN4(w16); PIN4(w17);
    PIN4(w20); PIN4(w21); PIN4(w22); PIN4(w23); PIN4(w24); PIN4(w25); PIN4(w26); PIN4(w27);
    PIN4(w30); PIN4(w31); PIN4(w32); PIN4(w33); PIN4(w34); PIN4(w35); PIN4(w36); PIN4(w37);

    // ---- init h, c, xp(t=0), xp(t=1) ----
    *(float4*)&hbuf[0][tid * 4] = *(const float4*)&h0[dir * H2DIM + tid * 4];
    float creg = 0.f;
    float xpc0 = 0.f, xpc1 = 0.f, xpc2 = 0.f, xpc3 = 0.f;   // step t
    float xpn0 = 0.f, xpn1 = 0.f, xpn2 = 0.f, xpn3 = 0.f;   // step t+1
    if (kc == 0) {
        creg = c0[dir * H2DIM + unit];
        xpc0 = xp[xpbase + unit];
        xpc1 = xp[xpbase + unit + 1024];
        xpc2 = xp[xpbase + unit + 2048];
        xpc3 = xp[xpbase + unit + 3072];
        xpn0 = xp[xpbase + GDIM + unit];
        xpn1 = xp[xpbase + GDIM + unit + 1024];
        xpn2 = xp[xpbase + GDIM + unit + 2048];
        xpn3 = xp[xpbase + GDIM + unit + 3072];
    }
    __syncthreads();

    int budget = 4000000;   // hang-proof poll budget

    for (int t = 0; t < T_LEN; ++t) {
        const float* __restrict__ hb = hbuf[t & 1];

        // depth-2 prefetch: issue xp(t+2) now; consumed 2 steps from now,
        // so the poll loop's vmcnt(0) never waits on a fresh HBM miss.
        float xq0 = 0.f, xq1 = 0.f, xq2 = 0.f, xq3 = 0.f;
        const int tq = (t + 2 < T_LEN) ? (t + 2) : t;
        if (kc == 0) {
            const size_t base = xpbase + (size_t)tq * GDIM + unit;
            xq0 = xp[base];
            xq1 = xp[base + 1024];
            xq2 = xp[base + 2048];
            xq3 = xp[base + 3072];
        }

        // ---- h slices from LDS (broadcast across the two 32-lane halves) ----
        const float4 hv0 = *(const float4*)&hb[      kc * 4];
        const float4 hv1 = *(const float4*)&hb[128 + kc * 4];
        const float4 hv2 = *(const float4*)&hb[256 + kc * 4];
        const float4 hv3 = *(const float4*)&hb[384 + kc * 4];
        const float4 hv4 = *(const float4*)&hb[512 + kc * 4];
        const float4 hv5 = *(const float4*)&hb[640 + kc * 4];
        const float4 hv6 = *(const float4*)&hb[768 + kc * 4];
        const float4 hv7 = *(const float4*)&hb[896 + kc * 4];

        // ---- partial dots: 4 gate rows x 32 k-elems, weights in registers ----
        float p0 = DOT4(w00,hv0)+DOT4(w01,hv1)+DOT4(w02,hv2)+DOT4(w03,hv3)
                 + DOT4(w04,hv4)+DOT4(w05,hv5)+DOT4(w06,hv6)+DOT4(w07,hv7);
        float p1 = DOT4(w10,hv0)+DOT4(w11,hv1)+DOT4(w12,hv2)+DOT4(w13,hv3)
                 + DOT4(w14,hv4)+DOT4(w15,hv5)+DOT4(w16,hv6)+DOT4(w17,hv7);
        float p2 = DOT4(w20,hv0)+DOT4(w21,hv1)+DOT4(w22,hv2)+DOT4(w23,hv3)
                 + DOT4(w24,hv4)+DOT4(w25,hv5)+DOT4(w26,hv6)+DOT4(w27,hv7);
        float p3 = DOT4(w30,hv0)+DOT4(w31,hv1)+DOT4(w32,hv2)+DOT4(w33,hv3)
                 + DOT4(w34,hv4)+DOT4(w35,hv5)+DOT4(w36,hv6)+DOT4(w37,hv7);

        // ---- value-merging butterfly over 32 kc-lanes: 6 shfls ----
        const bool o1 = (kc & 1);
        float sa = o1 ? p0 : p1;
        float ra = __shfl_xor(sa, 1);
        float qa = (o1 ? p1 : p0) + ra;
        float sb = o1 ? p2 : p3;
        float rb = __shfl_xor(sb, 1);
        float qb = (o1 ? p3 : p2) + rb;
        const bool o2 = (kc & 2);
        float sc = o2 ? qa : qb;
        float rc = __shfl_xor(sc, 2);
        float r  = (o2 ? qb : qa) + rc;
        r += __shfl_xor(r, 4);
        r += __shfl_xor(r, 8);
        r += __shfl_xor(r, 16);
        // gather gates 1..3 onto lane kc==0 (3 shfls)
        const float g1 = __shfl_xor(r, 1);
        const float g2 = __shfl_xor(r, 2);
        const float g3 = __shfl_xor(r, 3);

        // ---- cell + publish on lane kc==0 (one per unit) ----
        if (kc == 0) {
            const float gi = r  + xpc0;
            const float gf = g1 + xpc1;
            const float gg = g2 + xpc2;
            const float go = g3 + xpc3;
            const float c  = sigm(gf) * creg + sigm(gi) * tanhf(gg);
            const float h  = sigm(go) * tanhf(c);
            creg = c;
            const int tg = dir ? (T_LEN - 1 - t) : t;
            hist[(size_t)tg * 2048 + dir * H2DIM + unit] = h;
            const unsigned long long pack =
                ((unsigned long long)(unsigned)(t + 1) << 32) |
                (unsigned long long)__float_as_uint(h);
            __hip_atomic_store(&slots[((size_t)((t + 1) & 1) * 2 + dir) * H2DIM + unit],
                               pack, __ATOMIC_RELAXED, __HIP_MEMORY_SCOPE_AGENT);
        }

        // ---- poll peers' h for step t+1; write NEXT-parity hbuf ----
        if (t + 1 < T_LEN) {
            const unsigned want = (unsigned)(t + 1);
            unsigned long long* sb4 = &slots[((size_t)((t + 1) & 1) * 2 + dir) * H2DIM + tid * 4];
            unsigned long long v0 = 0, v1 = 0, v2 = 0, v3 = 0;
            bool d0 = false, d1 = false, d2 = false, d3 = false;
            for (;;) {
                if (!d0) v0 = __hip_atomic_load(&sb4[0], __ATOMIC_RELAXED, __HIP_MEMORY_SCOPE_AGENT);
                if (!d1) v1 = __hip_atomic_load(&sb4[1], __ATOMIC_RELAXED, __HIP_MEMORY_SCOPE_AGENT);
                if (!d2) v2 = __hip_atomic_load(&sb4[2], __ATOMIC_RELAXED, __HIP_MEMORY_SCOPE_AGENT);
                if (!d3) v3 = __hip_atomic_load(&sb4[3], __ATOMIC_RELAXED, __HIP_MEMORY_SCOPE_AGENT);
                d0 = d0 || ((unsigned)(v0 >> 32) == want);
                d1 = d1 || ((unsigned)(v1 >> 32) == want);
                d2 = d2 || ((unsigned)(v2 >> 32) == want);
                d3 = d3 || ((unsigned)(v3 >> 32) == want);
                if (d0 && d1 && d2 && d3) break;
                if (--budget <= 0) break;                // hang-proof bail
                __builtin_amdgcn_s_sleep(1);
            }
            float4 hv;
            hv.x = __uint_as_float((unsigned)v0);
            hv.y = __uint_as_float((unsigned)v1);
            hv.z = __uint_as_float((unsigned)v2);
            hv.w = __uint_as_float((unsigned)v3);
            *(float4*)&hbuf[(t + 1) & 1][tid * 4] = hv;
        }
        __syncthreads();   // next-parity hbuf complete; safe to proceed
        xpc0 = xpn0; xpc1 = xpn1; xpc2 = xpn2; xpc3 = xpn3;
        xpn0 = xq0;  xpn1 = xq1;  xpn2 = xq2;  xpn3 = xq3;
    }
}

// ============================================================================
// Kernel 3: feats[t][n] = dot(hist[t], w_tag[n]) + b_tag[n]
// ============================================================================
__global__ __launch_bounds__(256)
void feats_kernel(const float* __restrict__ hist,
                  const float* __restrict__ w_tag,
                  const float* __restrict__ b_tag,
                  float* __restrict__ feats)
{
    const int t = blockIdx.x;
    const int tid = threadIdx.x;
    const float* __restrict__ hrow = hist + (size_t)t * 2048 + tid * 8;
    const float4 ha = *(const float4*)&hrow[0];
    const float4 hb = *(const float4*)&hrow[4];
    float p[4];
    #pragma unroll
    for (int n = 0; n < 4; ++n) {
        const float* __restrict__ wr = w_tag + n * 2048 + tid * 8;
        const float4 wa = *(const float4*)&wr[0];
        const float4 wb = *(const float4*)&wr[4];
        p[n] = ha.x*wa.x + ha.y*wa.y + ha.z*wa.z + ha.w*wa.w
             + hb.x*wb.x + hb.y*wb.y + hb.z*wb.z + hb.w*wb.w;
    }
    #pragma unroll
    for (int m = 32; m >= 1; m >>= 1) {
        #pragma unroll
        for (int n = 0; n < 4; ++n) p[n] += __shfl_down(p[n], m);
    }
    __shared__ float red[4][4];
    const int wv = tid >> 6;
    if ((tid & 63) == 0) {
        #pragma unroll
        for (int n = 0; n < 4; ++n) red[n][wv] = p[n];
    }
    __syncthreads();
    if (tid < 4)
        feats[(size_t)t * 4 + tid] = red[tid][0] + red[tid][1] + red[tid][2] + red[tid][3] + b_tag[tid];
}

// ============================================================================
// Kernel 4: Viterbi (4 tags): forward DP + backtrace, op-order matches ref.
// ============================================================================
__global__ __launch_bounds__(256)
void viterbi_kernel(const float* __restrict__ feats,
                    const float* __restrict__ trans,
                    float* __restrict__ out)
{
    __shared__ float fsh[T_LEN * 4];   // 64 KB
    __shared__ unsigned bp[T_LEN];     // 16 KB
    const int tid = threadIdx.x;
    for (int i = tid; i < T_LEN; i += 256)
        *(float4*)&fsh[i * 4] = *(const float4*)&feats[(size_t)i * 4];
    __syncthreads();
    if (tid == 0) {
        float tr[16];
        #pragma unroll
        for (int i = 0; i < 16; ++i) tr[i] = trans[i];
        float fv[4] = {NEGV, NEGV, NEGV, NEGV};
        fv[START_TAG] = 0.0f;
        for (int t = 0; t < T_LEN; ++t) {
            float nf[4]; unsigned pb = 0;
            #pragma unroll
            for (int n = 0; n < 4; ++n) {
                float m = fv[0] + tr[n * 4 + 0]; int bsel = 0;
                #pragma unroll
                for (int p = 1; p < 4; ++p) {
                    const float s = fv[p] + tr[n * 4 + p];
                    if (s > m) { m = s; bsel = p; }
                }
                nf[n] = m + fsh[t * 4 + n];
                pb |= (unsigned)bsel << (8 * n);
            }
            bp[t] = pb;
            fv[0] = nf[0]; fv[1] = nf[1]; fv[2] = nf[2]; fv[3] = nf[3];
        }
        float bm = fv[0] + tr[STOP_TAG * 4 + 0]; int best = 0;
        #pragma unroll
        for (int p = 1; p < 4; ++p) {
            const float s = fv[p] + tr[STOP_TAG * 4 + p];
            if (s > bm) { bm = s; best = p; }
        }
        out[0] = bm;
        int cur = best;
        for (int t = T_LEN - 1; t >= 0; --t) {
            out[1 + t] = (float)cur;
            cur = (int)((bp[t] >> (8 * cur)) & 0xffu);
        }
    }
}

// ============================================================================
extern "C" void kernel_launch(void* const* d_in, const int* in_sizes, int n_in,
                              void* d_out, int out_size, void* d_ws, size_t ws_size,
                              hipStream_t stream) {
    const float* x      = (const float*)d_in[0];
    const float* h0     = (const float*)d_in[1];
    const float* c0     = (const float*)d_in[2];
    const float* w_ih_f = (const float*)d_in[3];
    const float* w_hh_f = (const float*)d_in[4];
    const float* b_ih_f = (const float*)d_in[5];
    const float* b_hh_f = (const float*)d_in[6];
    const float* w_ih_b = (const float*)d_in[7];
    const float* w_hh_b = (const float*)d_in[8];
    const float* b_ih_b = (const float*)d_in[9];
    const float* b_hh_b = (const float*)d_in[10];
    const float* w_tag  = (const float*)d_in[11];
    const float* b_tag  = (const float*)d_in[12];
    const float* trans  = (const float*)d_in[13];
    float* out = (float*)d_out;

    if (ws_size < WS_NEED) return;   // signature: output stays poisoned

    char* ws = (char*)d_ws;
    float* xp    = (float*)(ws + XP_OFF);
    float* hist  = (float*)(ws + HIST_OFF);
    float* feats = (float*)(ws + FEATS_OFF);
    unsigned long long* slots = (unsigned long long*)(ws + SLOTS_OFF);

    hipMemsetAsync(slots, 0, SLOTS_BYTES, stream);

    dim3 ggrid(32, 32, 2);
    xp_gemm<<<ggrid, 256, 0, stream>>>(x, w_ih_f, w_ih_b, b_ih_f, b_hh_f, b_ih_b, b_hh_b, xp);

    void* ka[] = { (void*)&xp, (void*)&h0, (void*)&c0, (void*)&w_hh_f, (void*)&w_hh_b,
                   (void*)&hist, (void*)&slots };
    hipLaunchCooperativeKernel((void*)lstm_scan, dim3(256), dim3(256), ka, 0, stream);

    feats_kernel<<<T_LEN, 256, 0, stream>>>(hist, w_tag, b_tag, feats);
    viterbi_kernel<<<1, 256, 0, stream>>>(feats, trans, out);
}